// Round 10
// baseline (219.026 us; speedup 1.0000x reference)
//
#include <hip/hip_runtime.h>
#include <math.h>

#define TSEQ 2048
#define HIDDEN 1280
#define NH 16
#define HD 80
#define HDP 96
#define ATTN_SCALE 0.11180339887498949f

typedef __bf16 bf16x8 __attribute__((ext_vector_type(8)));
typedef float f32x4 __attribute__((ext_vector_type(4)));

__device__ inline float bf2f(ushort u){ union { unsigned int u; float f; } v; v.u = ((unsigned int)u) << 16; return v.f; }
__device__ inline ushort f2bf(float f){
  union { float f; unsigned int u; } v; v.f = f;
  unsigned int u = v.u;
  return (ushort)((u + 0x7fffu + ((u >> 16) & 1u)) >> 16);
}
__device__ inline float ldin(const void* p, size_t i, bool f32){
  return f32 ? ((const float*)p)[i] : bf2f(((const ushort*)p)[i]);
}
// async global->LDS, 16B per lane; lds base must be wave-uniform, lane i lands at base + i*16B
__device__ inline void gl_lds16(const ushort* gp, ushort* lds_base){
  __builtin_amdgcn_global_load_lds(
      (const __attribute__((address_space(1))) unsigned int*)gp,
      (__attribute__((address_space(3))) unsigned int*)lds_base, 16, 0, 0);
}

// ---------------- misc: dtype detect (block 0) + segment bounds (blocks 1..8) ----------------
__global__ void misc_k(const ushort* __restrict__ X, const int* __restrict__ seg,
                       int* __restrict__ flag, int* __restrict__ segS, int* __restrict__ segE){
  int b = blockIdx.x, tid = threadIdx.x;
  if (b == 0){
    int insane = 0;
    for (int i = tid; i < 2048; i += 256){
      ushort u = X[i];
      int e = (u >> 7) & 0xFF;
      int m = u & 0x7F;
      bool bad = (e >= 0xC0) || (e != 0 && e <= 0x30) || (e == 0 && m != 0);
      if (bad) insane++;
    }
    __shared__ int s[256];
    s[tid] = insane; __syncthreads();
    for (int st = 128; st > 0; st >>= 1){ if (tid < st) s[tid] += s[tid + st]; __syncthreads(); }
    if (tid == 0) *flag = (s[0] > 128) ? 1 : 0;   // 1 => fp32 inputs
  } else {
    int t = (b - 1) * 256 + tid;
    int id = seg[t];
    int lo = 0, hi = TSEQ;
    while (lo < hi){ int mid = (lo + hi) >> 1; if (seg[mid] < id) lo = mid + 1; else hi = mid; }
    segS[t] = lo;
    lo = 0; hi = TSEQ;
    while (lo < hi){ int mid = (lo + hi) >> 1; if (seg[mid] <= id) lo = mid + 1; else hi = mid; }
    segE[t] = lo;
  }
}

// ---------------- prep: X convert (blocks 0..2559) + WT1 (2560..7359) + WT2 (7360..8959) ----
__global__ void prep_k(const int* __restrict__ flag, const void* __restrict__ X,
                       const void* __restrict__ Wq, const void* __restrict__ Wp,
                       ushort* __restrict__ Xb, ushort* __restrict__ WT1, ushort* __restrict__ WT2){
  __shared__ ushort tile[32][33];
  const bool f32 = (*flag != 0);
  int b = blockIdx.x, tid = threadIdx.x;
  if (b < 2560){
    int i = (b * 256 + tid) * 4;
    ushort o[4];
    if (f32){
      float4 v = *reinterpret_cast<const float4*>((const float*)X + i);
      o[0] = f2bf(v.x); o[1] = f2bf(v.y); o[2] = f2bf(v.z); o[3] = f2bf(v.w);
    } else {
      *reinterpret_cast<ushort4*>(o) = *reinterpret_cast<const ushort4*>((const ushort*)X + i);
    }
    *reinterpret_cast<ushort4*>(Xb + i) = *reinterpret_cast<ushort4*>(o);
    return;
  }
  const void* in; ushort* out; int rows, cols, tb;
  if (b < 7360){ tb = b - 2560; in = Wq; out = WT1; rows = HIDDEN; cols = 3 * HIDDEN; }
  else         { tb = b - 7360; in = Wp; out = WT2; rows = HIDDEN; cols = HIDDEN; }
  int tpr = cols / 32;
  int bx = (tb % tpr) * 32, by = (tb / tpr) * 32;
  int tx = tid & 31, ty = tid >> 5;
  for (int i = ty; i < 32; i += 8){
    size_t idx = (size_t)(by + i) * cols + bx + tx;
    tile[i][tx] = f32 ? f2bf(((const float*)in)[idx]) : ((const ushort*)in)[idx];
  }
  __syncthreads();
  for (int i = ty; i < 32; i += 8)
    out[(size_t)(bx + i) * rows + by + tx] = tile[tx][i];
}

// ---------------- GEMM: C[M,N] = A[M,K] @ BT[N,K]^T + bias ----------------
// BK=64, global_load_lds width-16 staging, 8-group XOR bank swizzle (stride-64 rows).
// LDS row R phys col-group P holds logical group L = P ^ (R&7).
// MODE 0: contiguous bf16 out. MODE 1: out dtype per flag (1=fp32, 0=bf16).
template<int MODE>
__launch_bounds__(256, 2)
__global__ void gemm_k(const ushort* __restrict__ A, const ushort* __restrict__ BT,
                       const void* __restrict__ bias, int K, int N,
                       const int* __restrict__ flagp, void* __restrict__ out)
{
  __shared__ __align__(16) ushort As[128 * 64];
  __shared__ __align__(16) ushort Bs[128 * 64];
  const int tid = threadIdx.x;
  const int wave = tid >> 6, lane = tid & 63;
  const int quad = lane >> 4, c = lane & 15;
  const int m0 = blockIdx.y * 128, n0 = blockIdx.x * 128;
  const int wm = (wave & 1) * 64, wn = (wave >> 1) * 64;

  f32x4 acc[4][4];
  for (int i = 0; i < 4; i++) for (int j = 0; j < 4; j++) acc[i][j] = (f32x4){0.f,0.f,0.f,0.f};

  const int drow = lane >> 3;
  const int dcg  = lane & 7;
  const int L8   = ((dcg ^ drow) * 8);
  const ushort* Ab = A  + (size_t)(m0 + wave * 32 + drow) * K + L8;
  const ushort* Bb = BT + (size_t)(n0 + wave * 32 + drow) * K + L8;
  ushort* AsW = As + wave * 32 * 64;
  ushort* BsW = Bs + wave * 32 * 64;
  const size_t row8 = (size_t)8 * K;

  for (int k0 = 0; k0 < K; k0 += 64){
    for (int d = 0; d < 4; d++){
      gl_lds16(Ab + d * row8 + k0, AsW + d * 512);
      gl_lds16(Bb + d * row8 + k0, BsW + d * 512);
    }
    __syncthreads();
    for (int ks = 0; ks < 2; ks++){
      const int pq8 = (((ks * 4 + quad) ^ (c & 7)) * 8);
      bf16x8 af[4], bfv[4];
      for (int i = 0; i < 4; i++) af[i]  = *reinterpret_cast<const bf16x8*>(&As[(wm + i*16 + c) * 64 + pq8]);
      for (int j = 0; j < 4; j++) bfv[j] = *reinterpret_cast<const bf16x8*>(&Bs[(wn + j*16 + c) * 64 + pq8]);
      for (int i = 0; i < 4; i++)
        for (int j = 0; j < 4; j++)
          acc[i][j] = __builtin_amdgcn_mfma_f32_16x16x32_bf16(af[i], bfv[j], acc[i][j], 0, 0, 0);
    }
    __syncthreads();
  }

  const bool f32 = (*flagp != 0);

  for (int j = 0; j < 4; j++){
    int n = n0 + wn + j*16 + c;
    float bv = ldin(bias, n, f32);
    for (int i = 0; i < 4; i++){
      int mbase = m0 + wm + i*16 + quad*4;
      for (int rr = 0; rr < 4; rr++){
        float v = acc[i][j][rr] + bv;
        size_t idx = (size_t)(mbase + rr) * N + n;
        if (MODE == 1 && f32) ((float*)out)[idx] = v;
        else                  ((ushort*)out)[idx] = f2bf(v);
      }
    }
  }
}

// ---------------- reshape: RoPE Q/K (blocks 0..2047) + V transpose (2048..2559) ------------
__global__ void reshape_k(const int* __restrict__ flag, const ushort* __restrict__ qkv,
                          const void* __restrict__ rope,
                          ushort* __restrict__ Qh, ushort* __restrict__ Kh, ushort* __restrict__ Vt){
  __shared__ __align__(16) ushort shm[5632];
  int b = blockIdx.x, tid = threadIdx.x;
  if (b < 2048){
    ushort* row = shm;           // 3840
    ushort* rrow = shm + 3840;   // 40
    int t = b;
    for (int i = tid; i < 480; i += 256)
      *reinterpret_cast<uint4*>(&row[i * 8]) = *reinterpret_cast<const uint4*>(qkv + (size_t)t * 3840 + i * 8);
    if (tid < 40)
      rrow[tid] = f2bf(ldin(rope, t * 40 + tid, *flag != 0));
    __syncthreads();
    int w = tid;
    if (w < 160){
      int part = w / 80;                 // 0=Q, 1=K
      int hw = w - part * 80;
      int h = hw / 5, dr0 = (hw % 5) * 8;
      const ushort* src = &row[part * HIDDEN + h * HD];
      ushort* dst = (part ? Kh : Qh) + ((size_t)h * TSEQ + t) * HDP;
      ushort o0[8], o1[8];
      for (int d = 0; d < 8; d++){
        float th = bf2f(rrow[dr0 + d]);
        float cs = cosf(th), sn = sinf(th);
        float xr = bf2f(src[dr0 + d]);
        float xi = bf2f(src[dr0 + d + 40]);
        o0[d] = f2bf(xr * cs - xi * sn);
        o1[d] = f2bf(xr * sn + xi * cs);
      }
      *reinterpret_cast<uint4*>(dst + dr0)      = *reinterpret_cast<uint4*>(o0);
      *reinterpret_cast<uint4*>(dst + dr0 + 40) = *reinterpret_cast<uint4*>(o1);
    } else if (w < 224){
      int idx = w - 160;                 // 64 items: {Q,K} x 16h x 2seg
      int part = idx >> 5;
      int h = (idx & 31) >> 1, sg = idx & 1;
      ushort* dst = (part ? Kh : Qh) + ((size_t)h * TSEQ + t) * HDP + 80 + sg * 8;
      uint4 z = {0, 0, 0, 0};
      *reinterpret_cast<uint4*>(dst) = z;
    }
  } else {
    int vb = b - 2048;
    int h = vb & 15, t0 = (vb >> 4) * 64;
    const ushort* src = qkv + 2 * HIDDEN + h * HD;
    // tile[64][88]
    for (int w = tid; w < 640; w += 256){
      int r = w / 10, cc = (w % 10) * 8;
      *reinterpret_cast<uint4*>(&shm[r * 88 + cc]) = *reinterpret_cast<const uint4*>(src + (size_t)(t0 + r) * 3840 + cc);
    }
    __syncthreads();
    for (int w = tid; w < 320; w += 256){
      int d = w >> 2, sg = (w & 3) * 16;
      ushort tmp[16];
      for (int i = 0; i < 16; i++) tmp[i] = shm[(sg + i) * 88 + d];
      ushort* dst = Vt + ((size_t)h * HD + d) * TSEQ + t0 + sg;
      *reinterpret_cast<uint4*>(dst)     = *reinterpret_cast<uint4*>(tmp);
      *reinterpret_cast<uint4*>(dst + 8) = *reinterpret_cast<uint4*>(tmp + 8);
    }
  }
}

// ---------------- attention: 32 queries/wave, unnormalized softmax, XCD-swizzled, dbuf P ---
__launch_bounds__(64, 4)
__global__ void attn_k(const ushort* __restrict__ Qh, const ushort* __restrict__ Kh,
                       const ushort* __restrict__ Vt, const int* __restrict__ seg,
                       const int* __restrict__ segS, const int* __restrict__ segE,
                       ushort* __restrict__ Oh)
{
  __shared__ __align__(16) ushort Pm[2][2][512];
  int lane = threadIdx.x;
  int quad = lane >> 4, c = lane & 15;
  // XCD swizzle: 1024 blocks; xcd gets queries [xcd*256, xcd*256+256) for all heads.
  int b = blockIdx.x;
  int xcd = b & 7, slot = b >> 3;
  int h = slot & 15;
  int t0 = (xcd * 8 + (slot >> 4)) * 32;

  const ushort* Qb = Qh + (size_t)h * TSEQ * HDP;
  const ushort* Kb = Kh + (size_t)h * TSEQ * HDP;
  const ushort* Vb = Vt + (size_t)h * HD * TSEQ;

  bf16x8 aq0[3], aq1[3];
  for (int i = 0; i < 3; i++){
    aq0[i] = *reinterpret_cast<const bf16x8*>(Qb + (size_t)(t0 + c) * HDP + i * 32 + quad * 8);
    aq1[i] = *reinterpret_cast<const bf16x8*>(Qb + (size_t)(t0 + 16 + c) * HDP + i * 32 + quad * 8);
  }

  int segq0[4], segq1[4];
  for (int rr = 0; rr < 4; rr++){
    segq0[rr] = seg[t0 + quad * 4 + rr];
    segq1[rr] = seg[t0 + 16 + quad * 4 + rr];
  }

  int kstart = segS[t0] & ~31;
  int kend   = segE[t0 + 31];

  float lsum0[4] = {0.f,0.f,0.f,0.f}, lsum1[4] = {0.f,0.f,0.f,0.f};
  f32x4 acc0[5], acc1[5];
  for (int dt = 0; dt < 5; dt++){ acc0[dt] = (f32x4){0.f,0.f,0.f,0.f}; acc1[dt] = (f32x4){0.f,0.f,0.f,0.f}; }

  for (int kt = kstart; kt < kend; kt += 32){
    ushort* pm0 = &Pm[(kt >> 5) & 1][0][0];
    ushort* pm1 = &Pm[(kt >> 5) & 1][1][0];
    f32x4 s00 = (f32x4){0.f,0.f,0.f,0.f}, s01 = s00, s10 = s00, s11 = s00;
    for (int i = 0; i < 3; i++){
      bf16x8 bk0 = *reinterpret_cast<const bf16x8*>(Kb + (size_t)(kt + c) * HDP + i * 32 + quad * 8);
      bf16x8 bk1 = *reinterpret_cast<const bf16x8*>(Kb + (size_t)(kt + 16 + c) * HDP + i * 32 + quad * 8);
      s00 = __builtin_amdgcn_mfma_f32_16x16x32_bf16(aq0[i], bk0, s00, 0, 0, 0);
      s01 = __builtin_amdgcn_mfma_f32_16x16x32_bf16(aq0[i], bk1, s01, 0, 0, 0);
      s10 = __builtin_amdgcn_mfma_f32_16x16x32_bf16(aq1[i], bk0, s10, 0, 0, 0);
      s11 = __builtin_amdgcn_mfma_f32_16x16x32_bf16(aq1[i], bk1, s11, 0, 0, 0);
    }
    int segk0 = seg[kt + c];
    int segk1 = seg[kt + 16 + c];
    for (int rr = 0; rr < 4; rr++){
      float e00 = (segq0[rr] == segk0) ? __expf(fminf(s00[rr] * ATTN_SCALE, 30.f)) : 0.f;
      float e01 = (segq0[rr] == segk1) ? __expf(fminf(s01[rr] * ATTN_SCALE, 30.f)) : 0.f;
      float e10 = (segq1[rr] == segk0) ? __expf(fminf(s10[rr] * ATTN_SCALE, 30.f)) : 0.f;
      float e11 = (segq1[rr] == segk1) ? __expf(fminf(s11[rr] * ATTN_SCALE, 30.f)) : 0.f;
      ushort u00 = f2bf(e00), u01 = f2bf(e01), u10 = f2bf(e10), u11 = f2bf(e11);
      lsum0[rr] += bf2f(u00) + bf2f(u01);
      lsum1[rr] += bf2f(u10) + bf2f(u11);
      pm0[(quad * 4 + rr) * 32 + c]      = u00;
      pm0[(quad * 4 + rr) * 32 + 16 + c] = u01;
      pm1[(quad * 4 + rr) * 32 + c]      = u10;
      pm1[(quad * 4 + rr) * 32 + 16 + c] = u11;
    }
    __builtin_amdgcn_s_waitcnt(0xc07f);   // lgkmcnt(0): this wave's P writes landed
    __builtin_amdgcn_wave_barrier();
    bf16x8 pa0 = *reinterpret_cast<const bf16x8*>(pm0 + c * 32 + quad * 8);
    bf16x8 pa1 = *reinterpret_cast<const bf16x8*>(pm1 + c * 32 + quad * 8);
    for (int dt = 0; dt < 5; dt++){
      bf16x8 bv = *reinterpret_cast<const bf16x8*>(Vb + (size_t)(dt * 16 + c) * TSEQ + kt + quad * 8);
      acc0[dt] = __builtin_amdgcn_mfma_f32_16x16x32_bf16(pa0, bv, acc0[dt], 0, 0, 0);
      acc1[dt] = __builtin_amdgcn_mfma_f32_16x16x32_bf16(pa1, bv, acc1[dt], 0, 0, 0);
    }
    // no trailing barrier: next iteration writes the OTHER Pm buffer
  }

  float inv0[4], inv1[4];
  for (int rr = 0; rr < 4; rr++){
    float r0 = lsum0[rr], r1 = lsum1[rr];
    r0 += __shfl_xor(r0, 1); r0 += __shfl_xor(r0, 2); r0 += __shfl_xor(r0, 4); r0 += __shfl_xor(r0, 8);
    r1 += __shfl_xor(r1, 1); r1 += __shfl_xor(r1, 2); r1 += __shfl_xor(r1, 4); r1 += __shfl_xor(r1, 8);
    inv0[rr] = (r0 > 0.f) ? 1.0f / r0 : 0.f;
    inv1[rr] = (r1 > 0.f) ? 1.0f / r1 : 0.f;
  }
  for (int dt = 0; dt < 5; dt++)
    for (int rr = 0; rr < 4; rr++){
      int t = t0 + quad * 4 + rr;
      Oh[(size_t)t * HIDDEN + h * HD + dt * 16 + c]        = f2bf(acc0[dt][rr] * inv0[rr]);
      Oh[(size_t)(t + 16) * HIDDEN + h * HD + dt * 16 + c] = f2bf(acc1[dt][rr] * inv1[rr]);
    }
}

extern "C" void kernel_launch(void* const* d_in, const int* in_sizes, int n_in,
                              void* d_out, int out_size, void* d_ws, size_t ws_size,
                              hipStream_t stream)
{
  const void* X    = d_in[0];
  const void* rope = d_in[1];
  const int*  seg  = (const int*)d_in[2];
  const void* Wq   = d_in[3];
  const void* bq   = d_in[4];
  const void* Wp   = d_in[5];
  const void* bp   = d_in[6];

  char* ws = (char*)d_ws;
  size_t off = 0;
  auto alloc = [&](size_t bytes){ void* p = ws + off; off += (bytes + 255) & ~(size_t)255; return p; };
  int*    flag = (int*)alloc(4);
  int*    segS = (int*)alloc(TSEQ * 4);
  int*    segE = (int*)alloc(TSEQ * 4);
  ushort* Xb   = (ushort*)alloc((size_t)TSEQ * HIDDEN * 2);          // 5.24 MB (aliased by Oh later)
  ushort* Qh   = (ushort*)alloc((size_t)NH * TSEQ * HDP * 2);        // 6.29 MB
  ushort* Kh   = (ushort*)alloc((size_t)NH * TSEQ * HDP * 2);        // 6.29 MB
  ushort* Vt   = (ushort*)alloc((size_t)NH * HD * TSEQ * 2);         // 5.24 MB
  ushort* WT1  = (ushort*)alloc((size_t)3 * HIDDEN * HIDDEN * 2);    // 9.83 MB
  ushort* WT2  = (ushort*)alloc((size_t)HIDDEN * HIDDEN * 2);        // 3.28 MB
  ushort* qkv  = (ushort*)alloc((size_t)TSEQ * 3 * HIDDEN * 2);      // 15.73 MB
  ushort* Oh   = Xb;   // Xb dead after gemm<0>; attn writes Oh afterwards

  misc_k<<<9, 256, 0, stream>>>((const ushort*)X, seg, flag, segS, segE);
  prep_k<<<8960, 256, 0, stream>>>(flag, X, Wq, Wp, Xb, WT1, WT2);
  gemm_k<0><<<dim3(30, 16), 256, 0, stream>>>(Xb, WT1, bq, HIDDEN, 3 * HIDDEN, flag, qkv);
  reshape_k<<<2560, 256, 0, stream>>>(flag, qkv, rope, Qh, Kh, Vt);
  attn_k<<<1024, 64, 0, stream>>>(Qh, Kh, Vt, seg, segS, segE, Oh);
  gemm_k<1><<<dim3(10, 16), 256, 0, stream>>>(Oh, WT2, bp, HIDDEN, HIDDEN, flag, d_out);
}

// Round 11
// 218.894 us; speedup vs baseline: 1.0006x; 1.0006x over previous
//
#include <hip/hip_runtime.h>
#include <math.h>

#define TSEQ 2048
#define HIDDEN 1280
#define NH 16
#define HD 80
#define HDP 96
#define ATTN_SCALE 0.11180339887498949f

typedef __bf16 bf16x8 __attribute__((ext_vector_type(8)));
typedef float f32x4 __attribute__((ext_vector_type(4)));

__device__ inline float bf2f(ushort u){ union { unsigned int u; float f; } v; v.u = ((unsigned int)u) << 16; return v.f; }
__device__ inline ushort f2bf(float f){
  union { float f; unsigned int u; } v; v.f = f;
  unsigned int u = v.u;
  return (ushort)((u + 0x7fffu + ((u >> 16) & 1u)) >> 16);
}
__device__ inline float ldin(const void* p, size_t i, bool f32){
  return f32 ? ((const float*)p)[i] : bf2f(((const ushort*)p)[i]);
}
// async global->LDS, 16B per lane; lds base must be wave-uniform, lane i lands at base + i*16B
__device__ inline void gl_lds16(const ushort* gp, ushort* lds_base){
  __builtin_amdgcn_global_load_lds(
      (const __attribute__((address_space(1))) unsigned int*)gp,
      (__attribute__((address_space(3))) unsigned int*)lds_base, 16, 0, 0);
}

// ---------------- misc: dtype detect (block 0) + segment bounds (blocks 1..8) ----------------
__global__ void misc_k(const ushort* __restrict__ X, const int* __restrict__ seg,
                       int* __restrict__ flag, int* __restrict__ segS, int* __restrict__ segE){
  int b = blockIdx.x, tid = threadIdx.x;
  if (b == 0){
    int insane = 0;
    for (int i = tid; i < 2048; i += 256){
      ushort u = X[i];
      int e = (u >> 7) & 0xFF;
      int m = u & 0x7F;
      bool bad = (e >= 0xC0) || (e != 0 && e <= 0x30) || (e == 0 && m != 0);
      if (bad) insane++;
    }
    __shared__ int s[256];
    s[tid] = insane; __syncthreads();
    for (int st = 128; st > 0; st >>= 1){ if (tid < st) s[tid] += s[tid + st]; __syncthreads(); }
    if (tid == 0) *flag = (s[0] > 128) ? 1 : 0;   // 1 => fp32 inputs
  } else {
    int t = (b - 1) * 256 + tid;
    int id = seg[t];
    int lo = 0, hi = TSEQ;
    while (lo < hi){ int mid = (lo + hi) >> 1; if (seg[mid] < id) lo = mid + 1; else hi = mid; }
    segS[t] = lo;
    lo = 0; hi = TSEQ;
    while (lo < hi){ int mid = (lo + hi) >> 1; if (seg[mid] <= id) lo = mid + 1; else hi = mid; }
    segE[t] = lo;
  }
}

// ---------------- prep: X convert (blocks 0..2559) + WT1 (2560..7359) + WT2 (7360..8959) ----
__global__ void prep_k(const int* __restrict__ flag, const void* __restrict__ X,
                       const void* __restrict__ Wq, const void* __restrict__ Wp,
                       ushort* __restrict__ Xb, ushort* __restrict__ WT1, ushort* __restrict__ WT2){
  __shared__ ushort tile[32][33];
  const bool f32 = (*flag != 0);
  int b = blockIdx.x, tid = threadIdx.x;
  if (b < 2560){
    int i = (b * 256 + tid) * 4;
    ushort o[4];
    if (f32){
      float4 v = *reinterpret_cast<const float4*>((const float*)X + i);
      o[0] = f2bf(v.x); o[1] = f2bf(v.y); o[2] = f2bf(v.z); o[3] = f2bf(v.w);
    } else {
      *reinterpret_cast<ushort4*>(o) = *reinterpret_cast<const ushort4*>((const ushort*)X + i);
    }
    *reinterpret_cast<ushort4*>(Xb + i) = *reinterpret_cast<ushort4*>(o);
    return;
  }
  const void* in; ushort* out; int rows, cols, tb;
  if (b < 7360){ tb = b - 2560; in = Wq; out = WT1; rows = HIDDEN; cols = 3 * HIDDEN; }
  else         { tb = b - 7360; in = Wp; out = WT2; rows = HIDDEN; cols = HIDDEN; }
  int tpr = cols / 32;
  int bx = (tb % tpr) * 32, by = (tb / tpr) * 32;
  int tx = tid & 31, ty = tid >> 5;
  for (int i = ty; i < 32; i += 8){
    size_t idx = (size_t)(by + i) * cols + bx + tx;
    tile[i][tx] = f32 ? f2bf(((const float*)in)[idx]) : ((const ushort*)in)[idx];
  }
  __syncthreads();
  for (int i = ty; i < 32; i += 8)
    out[(size_t)(bx + i) * rows + by + tx] = tile[tx][i];
}

// ---------------- GEMM: C[M,N] = A[M,K] @ BT[N,K]^T + bias ----------------
// BK=64, global_load_lds width-16 staging, 8-group XOR bank swizzle (stride-64 rows).
// MODE 0: contiguous bf16 out. MODE 1: out dtype per flag (1=fp32, 0=bf16).
template<int MODE>
__launch_bounds__(256, 2)
__global__ void gemm_k(const ushort* __restrict__ A, const ushort* __restrict__ BT,
                       const void* __restrict__ bias, int K, int N,
                       const int* __restrict__ flagp, void* __restrict__ out)
{
  __shared__ __align__(16) ushort As[128 * 64];
  __shared__ __align__(16) ushort Bs[128 * 64];
  const int tid = threadIdx.x;
  const int wave = tid >> 6, lane = tid & 63;
  const int quad = lane >> 4, c = lane & 15;
  const int m0 = blockIdx.y * 128, n0 = blockIdx.x * 128;
  const int wm = (wave & 1) * 64, wn = (wave >> 1) * 64;

  f32x4 acc[4][4];
  for (int i = 0; i < 4; i++) for (int j = 0; j < 4; j++) acc[i][j] = (f32x4){0.f,0.f,0.f,0.f};

  const int drow = lane >> 3;
  const int dcg  = lane & 7;
  const int L8   = ((dcg ^ drow) * 8);
  const ushort* Ab = A  + (size_t)(m0 + wave * 32 + drow) * K + L8;
  const ushort* Bb = BT + (size_t)(n0 + wave * 32 + drow) * K + L8;
  ushort* AsW = As + wave * 32 * 64;
  ushort* BsW = Bs + wave * 32 * 64;
  const size_t row8 = (size_t)8 * K;

  for (int k0 = 0; k0 < K; k0 += 64){
    for (int d = 0; d < 4; d++){
      gl_lds16(Ab + d * row8 + k0, AsW + d * 512);
      gl_lds16(Bb + d * row8 + k0, BsW + d * 512);
    }
    __syncthreads();
    for (int ks = 0; ks < 2; ks++){
      const int pq8 = (((ks * 4 + quad) ^ (c & 7)) * 8);
      bf16x8 af[4], bfv[4];
      for (int i = 0; i < 4; i++) af[i]  = *reinterpret_cast<const bf16x8*>(&As[(wm + i*16 + c) * 64 + pq8]);
      for (int j = 0; j < 4; j++) bfv[j] = *reinterpret_cast<const bf16x8*>(&Bs[(wn + j*16 + c) * 64 + pq8]);
      for (int i = 0; i < 4; i++)
        for (int j = 0; j < 4; j++)
          acc[i][j] = __builtin_amdgcn_mfma_f32_16x16x32_bf16(af[i], bfv[j], acc[i][j], 0, 0, 0);
    }
    __syncthreads();
  }

  const bool f32 = (*flagp != 0);

  for (int j = 0; j < 4; j++){
    int n = n0 + wn + j*16 + c;
    float bv = ldin(bias, n, f32);
    for (int i = 0; i < 4; i++){
      int mbase = m0 + wm + i*16 + quad*4;
      for (int rr = 0; rr < 4; rr++){
        float v = acc[i][j][rr] + bv;
        size_t idx = (size_t)(mbase + rr) * N + n;
        if (MODE == 1 && f32) ((float*)out)[idx] = v;
        else                  ((ushort*)out)[idx] = f2bf(v);
      }
    }
  }
}

// ---------------- reshape: RoPE Q/K (blocks 0..2047) + V transpose (2048..2559) ------------
__global__ void reshape_k(const int* __restrict__ flag, const ushort* __restrict__ qkv,
                          const void* __restrict__ rope,
                          ushort* __restrict__ Qh, ushort* __restrict__ Kh, ushort* __restrict__ Vt){
  __shared__ __align__(16) ushort shm[5632];
  int b = blockIdx.x, tid = threadIdx.x;
  if (b < 2048){
    ushort* row = shm;           // 3840
    ushort* rrow = shm + 3840;   // 40
    int t = b;
    for (int i = tid; i < 480; i += 256)
      *reinterpret_cast<uint4*>(&row[i * 8]) = *reinterpret_cast<const uint4*>(qkv + (size_t)t * 3840 + i * 8);
    if (tid < 40)
      rrow[tid] = f2bf(ldin(rope, t * 40 + tid, *flag != 0));
    __syncthreads();
    int w = tid;
    if (w < 160){
      int part = w / 80;                 // 0=Q, 1=K
      int hw = w - part * 80;
      int h = hw / 5, dr0 = (hw % 5) * 8;
      const ushort* src = &row[part * HIDDEN + h * HD];
      ushort* dst = (part ? Kh : Qh) + ((size_t)h * TSEQ + t) * HDP;
      ushort o0[8], o1[8];
      for (int d = 0; d < 8; d++){
        float th = bf2f(rrow[dr0 + d]);
        float cs = cosf(th), sn = sinf(th);
        float xr = bf2f(src[dr0 + d]);
        float xi = bf2f(src[dr0 + d + 40]);
        o0[d] = f2bf(xr * cs - xi * sn);
        o1[d] = f2bf(xr * sn + xi * cs);
      }
      *reinterpret_cast<uint4*>(dst + dr0)      = *reinterpret_cast<uint4*>(o0);
      *reinterpret_cast<uint4*>(dst + dr0 + 40) = *reinterpret_cast<uint4*>(o1);
    } else if (w < 224){
      int idx = w - 160;                 // 64 items: {Q,K} x 16h x 2seg
      int part = idx >> 5;
      int h = (idx & 31) >> 1, sg = idx & 1;
      ushort* dst = (part ? Kh : Qh) + ((size_t)h * TSEQ + t) * HDP + 80 + sg * 8;
      uint4 z = {0, 0, 0, 0};
      *reinterpret_cast<uint4*>(dst) = z;
    }
  } else {
    int vb = b - 2048;
    int h = vb & 15, t0 = (vb >> 4) * 64;
    const ushort* src = qkv + 2 * HIDDEN + h * HD;
    // tile[64][88]
    for (int w = tid; w < 640; w += 256){
      int r = w / 10, cc = (w % 10) * 8;
      *reinterpret_cast<uint4*>(&shm[r * 88 + cc]) = *reinterpret_cast<const uint4*>(src + (size_t)(t0 + r) * 3840 + cc);
    }
    __syncthreads();
    for (int w = tid; w < 320; w += 256){
      int d = w >> 2, sg = (w & 3) * 16;
      ushort tmp[16];
      for (int i = 0; i < 16; i++) tmp[i] = shm[(sg + i) * 88 + d];
      ushort* dst = Vt + ((size_t)h * HD + d) * TSEQ + t0 + sg;
      *reinterpret_cast<uint4*>(dst)     = *reinterpret_cast<uint4*>(tmp);
      *reinterpret_cast<uint4*>(dst + 8) = *reinterpret_cast<uint4*>(tmp + 8);
    }
  }
}

// ---------------- attention: 16 q/tile, 2 waves split the k-range (additive partials) ------
// Unnormalized softmax => partials combine by simple addition (no max rescale).
__launch_bounds__(128, 4)
__global__ void attn_k(const ushort* __restrict__ Qh, const ushort* __restrict__ Kh,
                       const ushort* __restrict__ Vt, const int* __restrict__ seg,
                       const int* __restrict__ segS, const int* __restrict__ segE,
                       ushort* __restrict__ Oh)
{
  __shared__ __align__(16) ushort Pm[2][2][512];   // [wave][dbuf][16*32]
  __shared__ float accS[5][64][4];                 // wave1 partial O
  __shared__ float lsumS[64][4];                   // wave1 partial l
  int tid = threadIdx.x;
  int wave = tid >> 6, lane = tid & 63;
  int quad = lane >> 4, c = lane & 15;
  // XCD swizzle: same 256-query range -> same XCD's L2.
  int b = blockIdx.x;
  int xcd = b & 7, slot = b >> 3;
  int h = slot & 15;
  int t0 = (xcd * 16 + (slot >> 4)) * 16;

  const ushort* Qb = Qh + (size_t)h * TSEQ * HDP;
  const ushort* Kb = Kh + (size_t)h * TSEQ * HDP;
  const ushort* Vb = Vt + (size_t)h * HD * TSEQ;

  bf16x8 aq[3];
  for (int i = 0; i < 3; i++)
    aq[i] = *reinterpret_cast<const bf16x8*>(Qb + (size_t)(t0 + c) * HDP + i * 32 + quad * 8);

  int segq[4];
  for (int rr = 0; rr < 4; rr++) segq[rr] = seg[t0 + quad * 4 + rr];

  int kstart = segS[t0] & ~31;
  int kend   = segE[t0 + 15];

  float lsum[4] = {0.f, 0.f, 0.f, 0.f};
  f32x4 accd[5];
  for (int dt = 0; dt < 5; dt++) accd[dt] = (f32x4){0.f,0.f,0.f,0.f};

  // wave-interleaved k tiles: wave0 = kstart, kstart+64, ...; wave1 = kstart+32, ...
  for (int kt = kstart + wave * 32; kt < kend; kt += 64){
    ushort* pm = &Pm[wave][(kt >> 6) & 1][0];
    f32x4 s0 = (f32x4){0.f,0.f,0.f,0.f}, s1 = (f32x4){0.f,0.f,0.f,0.f};
    for (int i = 0; i < 3; i++){
      bf16x8 bk0 = *reinterpret_cast<const bf16x8*>(Kb + (size_t)(kt + c) * HDP + i * 32 + quad * 8);
      s0 = __builtin_amdgcn_mfma_f32_16x16x32_bf16(aq[i], bk0, s0, 0, 0, 0);
      bf16x8 bk1 = *reinterpret_cast<const bf16x8*>(Kb + (size_t)(kt + 16 + c) * HDP + i * 32 + quad * 8);
      s1 = __builtin_amdgcn_mfma_f32_16x16x32_bf16(aq[i], bk1, s1, 0, 0, 0);
    }
    int segk0 = seg[kt + c];
    int segk1 = seg[kt + 16 + c];
    for (int rr = 0; rr < 4; rr++){
      bool ok0 = (segq[rr] == segk0);
      bool ok1 = (segq[rr] == segk1);
      float e0 = ok0 ? __expf(fminf(s0[rr] * ATTN_SCALE, 30.f)) : 0.f;
      float e1 = ok1 ? __expf(fminf(s1[rr] * ATTN_SCALE, 30.f)) : 0.f;
      ushort u0 = f2bf(e0), u1 = f2bf(e1);
      lsum[rr] += bf2f(u0) + bf2f(u1);       // l consistent with bf16 P
      pm[(quad * 4 + rr) * 32 + c]      = u0;
      pm[(quad * 4 + rr) * 32 + 16 + c] = u1;
    }
    __builtin_amdgcn_s_waitcnt(0xc07f);   // lgkmcnt(0): this wave's P writes landed
    __builtin_amdgcn_wave_barrier();
    bf16x8 pa = *reinterpret_cast<const bf16x8*>(pm + c * 32 + quad * 8);
    for (int dt = 0; dt < 5; dt++){
      bf16x8 bv = *reinterpret_cast<const bf16x8*>(Vb + (size_t)(dt * 16 + c) * TSEQ + kt + quad * 8);
      accd[dt] = __builtin_amdgcn_mfma_f32_16x16x32_bf16(pa, bv, accd[dt], 0, 0, 0);
    }
    // no trailing barrier: this wave's next iteration writes its OTHER Pm buffer
  }

  // combine the two waves' partials (pure addition — unnormalized softmax)
  if (wave == 1){
    for (int dt = 0; dt < 5; dt++)
      for (int rr = 0; rr < 4; rr++) accS[dt][lane][rr] = accd[dt][rr];
    for (int rr = 0; rr < 4; rr++) lsumS[lane][rr] = lsum[rr];
  }
  __syncthreads();
  if (wave == 0){
    for (int dt = 0; dt < 5; dt++)
      for (int rr = 0; rr < 4; rr++) accd[dt][rr] += accS[dt][lane][rr];
    for (int rr = 0; rr < 4; rr++) lsum[rr] += lsumS[lane][rr];

    float inv[4];
    for (int rr = 0; rr < 4; rr++){
      float rs = lsum[rr];
      rs += __shfl_xor(rs, 1);
      rs += __shfl_xor(rs, 2);
      rs += __shfl_xor(rs, 4);
      rs += __shfl_xor(rs, 8);
      inv[rr] = (rs > 0.f) ? 1.0f / rs : 0.f;
    }
    for (int dt = 0; dt < 5; dt++)
      for (int rr = 0; rr < 4; rr++){
        int t = t0 + quad * 4 + rr;
        Oh[(size_t)t * HIDDEN + h * HD + dt * 16 + c] = f2bf(accd[dt][rr] * inv[rr]);
      }
  }
}

extern "C" void kernel_launch(void* const* d_in, const int* in_sizes, int n_in,
                              void* d_out, int out_size, void* d_ws, size_t ws_size,
                              hipStream_t stream)
{
  const void* X    = d_in[0];
  const void* rope = d_in[1];
  const int*  seg  = (const int*)d_in[2];
  const void* Wq   = d_in[3];
  const void* bq   = d_in[4];
  const void* Wp   = d_in[5];
  const void* bp   = d_in[6];

  char* ws = (char*)d_ws;
  size_t off = 0;
  auto alloc = [&](size_t bytes){ void* p = ws + off; off += (bytes + 255) & ~(size_t)255; return p; };
  int*    flag = (int*)alloc(4);
  int*    segS = (int*)alloc(TSEQ * 4);
  int*    segE = (int*)alloc(TSEQ * 4);
  ushort* Xb   = (ushort*)alloc((size_t)TSEQ * HIDDEN * 2);          // 5.24 MB (aliased by Oh later)
  ushort* Qh   = (ushort*)alloc((size_t)NH * TSEQ * HDP * 2);        // 6.29 MB
  ushort* Kh   = (ushort*)alloc((size_t)NH * TSEQ * HDP * 2);        // 6.29 MB
  ushort* Vt   = (ushort*)alloc((size_t)NH * HD * TSEQ * 2);         // 5.24 MB
  ushort* WT1  = (ushort*)alloc((size_t)3 * HIDDEN * HIDDEN * 2);    // 9.83 MB
  ushort* WT2  = (ushort*)alloc((size_t)HIDDEN * HIDDEN * 2);        // 3.28 MB
  ushort* qkv  = (ushort*)alloc((size_t)TSEQ * 3 * HIDDEN * 2);      // 15.73 MB
  ushort* Oh   = Xb;   // Xb dead after gemm<0>; attn writes Oh afterwards

  misc_k<<<9, 256, 0, stream>>>((const ushort*)X, seg, flag, segS, segE);
  prep_k<<<8960, 256, 0, stream>>>(flag, X, Wq, Wp, Xb, WT1, WT2);
  gemm_k<0><<<dim3(30, 16), 256, 0, stream>>>(Xb, WT1, bq, HIDDEN, 3 * HIDDEN, flag, qkv);
  reshape_k<<<2560, 256, 0, stream>>>(flag, qkv, rope, Qh, Kh, Vt);
  attn_k<<<2048, 128, 0, stream>>>(Qh, Kh, Vt, seg, segS, segE, Oh);
  gemm_k<1><<<dim3(10, 16), 256, 0, stream>>>(Oh, WT2, bp, HIDDEN, HIDDEN, flag, d_out);
}

// Round 12
// 206.362 us; speedup vs baseline: 1.0614x; 1.0607x over previous
//
#include <hip/hip_runtime.h>
#include <math.h>

#define TSEQ 2048
#define HIDDEN 1280
#define NH 16
#define HD 80
#define HDP 96
#define ATTN_SCALE 0.11180339887498949f

typedef __bf16 bf16x8 __attribute__((ext_vector_type(8)));
typedef float f32x4 __attribute__((ext_vector_type(4)));

__device__ inline float bf2f(ushort u){ union { unsigned int u; float f; } v; v.u = ((unsigned int)u) << 16; return v.f; }
__device__ inline ushort f2bf(float f){
  union { float f; unsigned int u; } v; v.f = f;
  unsigned int u = v.u;
  return (ushort)((u + 0x7fffu + ((u >> 16) & 1u)) >> 16);
}
__device__ inline float ldin(const void* p, size_t i, bool f32){
  return f32 ? ((const float*)p)[i] : bf2f(((const ushort*)p)[i]);
}
// async global->LDS, 16B per lane; lds base must be wave-uniform, lane i lands at base + i*16B
__device__ inline void gl_lds16(const ushort* gp, ushort* lds_base){
  __builtin_amdgcn_global_load_lds(
      (const __attribute__((address_space(1))) unsigned int*)gp,
      (__attribute__((address_space(3))) unsigned int*)lds_base, 16, 0, 0);
}

// ---------------- misc: dtype detect (block 0) + segment bounds (blocks 1..8) ----------------
__global__ void misc_k(const ushort* __restrict__ X, const int* __restrict__ seg,
                       int* __restrict__ flag, int* __restrict__ segS, int* __restrict__ segE){
  int b = blockIdx.x, tid = threadIdx.x;
  if (b == 0){
    int insane = 0;
    for (int i = tid; i < 2048; i += 256){
      ushort u = X[i];
      int e = (u >> 7) & 0xFF;
      int m = u & 0x7F;
      bool bad = (e >= 0xC0) || (e != 0 && e <= 0x30) || (e == 0 && m != 0);
      if (bad) insane++;
    }
    __shared__ int s[256];
    s[tid] = insane; __syncthreads();
    for (int st = 128; st > 0; st >>= 1){ if (tid < st) s[tid] += s[tid + st]; __syncthreads(); }
    if (tid == 0) *flag = (s[0] > 128) ? 1 : 0;   // 1 => fp32 inputs
  } else {
    int t = (b - 1) * 256 + tid;
    int id = seg[t];
    int lo = 0, hi = TSEQ;
    while (lo < hi){ int mid = (lo + hi) >> 1; if (seg[mid] < id) lo = mid + 1; else hi = mid; }
    segS[t] = lo;
    lo = 0; hi = TSEQ;
    while (lo < hi){ int mid = (lo + hi) >> 1; if (seg[mid] <= id) lo = mid + 1; else hi = mid; }
    segE[t] = lo;
  }
}

// ---------------- prep: X convert (blocks 0..2559) + WT1 (2560..7359) + WT2 (7360..8959) ----
__global__ void prep_k(const int* __restrict__ flag, const void* __restrict__ X,
                       const void* __restrict__ Wq, const void* __restrict__ Wp,
                       ushort* __restrict__ Xb, ushort* __restrict__ WT1, ushort* __restrict__ WT2){
  __shared__ ushort tile[32][33];
  const bool f32 = (*flag != 0);
  int b = blockIdx.x, tid = threadIdx.x;
  if (b < 2560){
    int i = (b * 256 + tid) * 4;
    ushort o[4];
    if (f32){
      float4 v = *reinterpret_cast<const float4*>((const float*)X + i);
      o[0] = f2bf(v.x); o[1] = f2bf(v.y); o[2] = f2bf(v.z); o[3] = f2bf(v.w);
    } else {
      *reinterpret_cast<ushort4*>(o) = *reinterpret_cast<const ushort4*>((const ushort*)X + i);
    }
    *reinterpret_cast<ushort4*>(Xb + i) = *reinterpret_cast<ushort4*>(o);
    return;
  }
  const void* in; ushort* out; int rows, cols, tb;
  if (b < 7360){ tb = b - 2560; in = Wq; out = WT1; rows = HIDDEN; cols = 3 * HIDDEN; }
  else         { tb = b - 7360; in = Wp; out = WT2; rows = HIDDEN; cols = HIDDEN; }
  int tpr = cols / 32;
  int bx = (tb % tpr) * 32, by = (tb / tpr) * 32;
  int tx = tid & 31, ty = tid >> 5;
  for (int i = ty; i < 32; i += 8){
    size_t idx = (size_t)(by + i) * cols + bx + tx;
    tile[i][tx] = f32 ? f2bf(((const float*)in)[idx]) : ((const ushort*)in)[idx];
  }
  __syncthreads();
  for (int i = ty; i < 32; i += 8)
    out[(size_t)(bx + i) * rows + by + tx] = tile[tx][i];
}

// ---------------- GEMM: C[M,N] = A[M,K] @ BT[N,K]^T + bias ----------------
// BK=64, dbuf LDS, global_load_lds staging gated by raw vmcnt(8) barriers (AITER-style),
// 8-group XOR bank swizzle. MODE 0: bf16 out. MODE 1: out dtype per flag.
template<int MODE>
__launch_bounds__(256, 2)
__global__ void gemm_k(const ushort* __restrict__ A, const ushort* __restrict__ BT,
                       const void* __restrict__ bias, int K, int N,
                       const int* __restrict__ flagp, void* __restrict__ out)
{
  __shared__ __align__(16) ushort As[2][128 * 64];
  __shared__ __align__(16) ushort Bs[2][128 * 64];
  const int tid = threadIdx.x;
  const int wave = tid >> 6, lane = tid & 63;
  const int quad = lane >> 4, c = lane & 15;
  const int m0 = blockIdx.y * 128, n0 = blockIdx.x * 128;
  const int wm = (wave & 1) * 64, wn = (wave >> 1) * 64;

  f32x4 acc[4][4];
  for (int i = 0; i < 4; i++) for (int j = 0; j < 4; j++) acc[i][j] = (f32x4){0.f,0.f,0.f,0.f};

  const int drow = lane >> 3;
  const int dcg  = lane & 7;
  const int L8   = ((dcg ^ drow) * 8);
  const ushort* Ab = A  + (size_t)(m0 + wave * 32 + drow) * K + L8;
  const ushort* Bb = BT + (size_t)(n0 + wave * 32 + drow) * K + L8;
  const size_t row8 = (size_t)8 * K;
  const int woff = wave * 32 * 64;

  // prologue: stage tile 0 into buffer 0 (8 DMAs per wave)
  for (int d = 0; d < 4; d++){
    gl_lds16(Ab + d * row8, As[0] + woff + d * 512);
    gl_lds16(Bb + d * row8, Bs[0] + woff + d * 512);
  }

  int cur = 0;
  for (int k0 = 0; k0 < K; k0 += 64){
    if (k0 + 64 < K){
      int nxt = cur ^ 1;
      for (int d = 0; d < 4; d++){
        gl_lds16(Ab + d * row8 + k0 + 64, As[nxt] + woff + d * 512);
        gl_lds16(Bb + d * row8 + k0 + 64, Bs[nxt] + woff + d * 512);
      }
      // wait only for the PREVIOUS tile's 8 DMAs; the fresh 8 stay in flight
      asm volatile("s_waitcnt vmcnt(8)\ns_barrier" ::: "memory");
    } else {
      asm volatile("s_waitcnt vmcnt(0)\ns_barrier" ::: "memory");
    }
    const ushort* Ac = As[cur];
    const ushort* Bc = Bs[cur];
    for (int ks = 0; ks < 2; ks++){
      const int pq8 = (((ks * 4 + quad) ^ (c & 7)) * 8);
      bf16x8 af[4], bfv[4];
      for (int i = 0; i < 4; i++) af[i]  = *reinterpret_cast<const bf16x8*>(&Ac[(wm + i*16 + c) * 64 + pq8]);
      for (int j = 0; j < 4; j++) bfv[j] = *reinterpret_cast<const bf16x8*>(&Bc[(wn + j*16 + c) * 64 + pq8]);
      for (int i = 0; i < 4; i++)
        for (int j = 0; j < 4; j++)
          acc[i][j] = __builtin_amdgcn_mfma_f32_16x16x32_bf16(af[i], bfv[j], acc[i][j], 0, 0, 0);
    }
    // all waves must finish reading 'cur' before next iteration's DMA overwrites it
    asm volatile("s_waitcnt lgkmcnt(0)\ns_barrier" ::: "memory");
    cur ^= 1;
  }

  const bool f32 = (*flagp != 0);

  for (int j = 0; j < 4; j++){
    int n = n0 + wn + j*16 + c;
    float bv = ldin(bias, n, f32);
    for (int i = 0; i < 4; i++){
      int mbase = m0 + wm + i*16 + quad*4;
      for (int rr = 0; rr < 4; rr++){
        float v = acc[i][j][rr] + bv;
        size_t idx = (size_t)(mbase + rr) * N + n;
        if (MODE == 1 && f32) ((float*)out)[idx] = v;
        else                  ((ushort*)out)[idx] = f2bf(v);
      }
    }
  }
}

// ---------------- reshape: RoPE Q/K (blocks 0..2047) + V transpose (2048..2559) ------------
__global__ void reshape_k(const int* __restrict__ flag, const ushort* __restrict__ qkv,
                          const void* __restrict__ rope,
                          ushort* __restrict__ Qh, ushort* __restrict__ Kh, ushort* __restrict__ Vt){
  __shared__ __align__(16) ushort shm[5632];
  int b = blockIdx.x, tid = threadIdx.x;
  if (b < 2048){
    ushort* row = shm;           // 3840
    ushort* rrow = shm + 3840;   // 40
    int t = b;
    for (int i = tid; i < 480; i += 256)
      *reinterpret_cast<uint4*>(&row[i * 8]) = *reinterpret_cast<const uint4*>(qkv + (size_t)t * 3840 + i * 8);
    if (tid < 40)
      rrow[tid] = f2bf(ldin(rope, t * 40 + tid, *flag != 0));
    __syncthreads();
    int w = tid;
    if (w < 160){
      int part = w / 80;                 // 0=Q, 1=K
      int hw = w - part * 80;
      int h = hw / 5, dr0 = (hw % 5) * 8;
      const ushort* src = &row[part * HIDDEN + h * HD];
      ushort* dst = (part ? Kh : Qh) + ((size_t)h * TSEQ + t) * HDP;
      ushort o0[8], o1[8];
      for (int d = 0; d < 8; d++){
        float th = bf2f(rrow[dr0 + d]);
        float cs = cosf(th), sn = sinf(th);
        float xr = bf2f(src[dr0 + d]);
        float xi = bf2f(src[dr0 + d + 40]);
        o0[d] = f2bf(xr * cs - xi * sn);
        o1[d] = f2bf(xr * sn + xi * cs);
      }
      *reinterpret_cast<uint4*>(dst + dr0)      = *reinterpret_cast<uint4*>(o0);
      *reinterpret_cast<uint4*>(dst + dr0 + 40) = *reinterpret_cast<uint4*>(o1);
    } else if (w < 224){
      int idx = w - 160;                 // 64 items: {Q,K} x 16h x 2seg
      int part = idx >> 5;
      int h = (idx & 31) >> 1, sg = idx & 1;
      ushort* dst = (part ? Kh : Qh) + ((size_t)h * TSEQ + t) * HDP + 80 + sg * 8;
      uint4 z = {0, 0, 0, 0};
      *reinterpret_cast<uint4*>(dst) = z;
    }
  } else {
    int vb = b - 2048;
    int h = vb & 15, t0 = (vb >> 4) * 64;
    const ushort* src = qkv + 2 * HIDDEN + h * HD;
    // tile[64][88]
    for (int w = tid; w < 640; w += 256){
      int r = w / 10, cc = (w % 10) * 8;
      *reinterpret_cast<uint4*>(&shm[r * 88 + cc]) = *reinterpret_cast<const uint4*>(src + (size_t)(t0 + r) * 3840 + cc);
    }
    __syncthreads();
    for (int w = tid; w < 320; w += 256){
      int d = w >> 2, sg = (w & 3) * 16;
      ushort tmp[16];
      for (int i = 0; i < 16; i++) tmp[i] = shm[(sg + i) * 88 + d];
      ushort* dst = Vt + ((size_t)h * HD + d) * TSEQ + t0 + sg;
      *reinterpret_cast<uint4*>(dst)     = *reinterpret_cast<uint4*>(tmp);
      *reinterpret_cast<uint4*>(dst + 8) = *reinterpret_cast<uint4*>(tmp + 8);
    }
  }
}

// ---------------- attention: 16 q/tile, 2 waves split the k-range (additive partials) ------
__launch_bounds__(128, 4)
__global__ void attn_k(const ushort* __restrict__ Qh, const ushort* __restrict__ Kh,
                       const ushort* __restrict__ Vt, const int* __restrict__ seg,
                       const int* __restrict__ segS, const int* __restrict__ segE,
                       ushort* __restrict__ Oh)
{
  __shared__ __align__(16) ushort Pm[2][2][512];   // [wave][dbuf][16*32]
  __shared__ float accS[5][64][4];                 // wave1 partial O
  __shared__ float lsumS[64][4];                   // wave1 partial l
  int tid = threadIdx.x;
  int wave = tid >> 6, lane = tid & 63;
  int quad = lane >> 4, c = lane & 15;
  int b = blockIdx.x;
  int xcd = b & 7, slot = b >> 3;
  int h = slot & 15;
  int t0 = (xcd * 16 + (slot >> 4)) * 16;

  const ushort* Qb = Qh + (size_t)h * TSEQ * HDP;
  const ushort* Kb = Kh + (size_t)h * TSEQ * HDP;
  const ushort* Vb = Vt + (size_t)h * HD * TSEQ;

  bf16x8 aq[3];
  for (int i = 0; i < 3; i++)
    aq[i] = *reinterpret_cast<const bf16x8*>(Qb + (size_t)(t0 + c) * HDP + i * 32 + quad * 8);

  int segq[4];
  for (int rr = 0; rr < 4; rr++) segq[rr] = seg[t0 + quad * 4 + rr];

  int kstart = segS[t0] & ~31;
  int kend   = segE[t0 + 15];

  float lsum[4] = {0.f, 0.f, 0.f, 0.f};
  f32x4 accd[5];
  for (int dt = 0; dt < 5; dt++) accd[dt] = (f32x4){0.f,0.f,0.f,0.f};

  for (int kt = kstart + wave * 32; kt < kend; kt += 64){
    ushort* pm = &Pm[wave][(kt >> 6) & 1][0];
    f32x4 s0 = (f32x4){0.f,0.f,0.f,0.f}, s1 = (f32x4){0.f,0.f,0.f,0.f};
    for (int i = 0; i < 3; i++){
      bf16x8 bk0 = *reinterpret_cast<const bf16x8*>(Kb + (size_t)(kt + c) * HDP + i * 32 + quad * 8);
      s0 = __builtin_amdgcn_mfma_f32_16x16x32_bf16(aq[i], bk0, s0, 0, 0, 0);
      bf16x8 bk1 = *reinterpret_cast<const bf16x8*>(Kb + (size_t)(kt + 16 + c) * HDP + i * 32 + quad * 8);
      s1 = __builtin_amdgcn_mfma_f32_16x16x32_bf16(aq[i], bk1, s1, 0, 0, 0);
    }
    int segk0 = seg[kt + c];
    int segk1 = seg[kt + 16 + c];
    for (int rr = 0; rr < 4; rr++){
      bool ok0 = (segq[rr] == segk0);
      bool ok1 = (segq[rr] == segk1);
      float e0 = ok0 ? __expf(fminf(s0[rr] * ATTN_SCALE, 30.f)) : 0.f;
      float e1 = ok1 ? __expf(fminf(s1[rr] * ATTN_SCALE, 30.f)) : 0.f;
      ushort u0 = f2bf(e0), u1 = f2bf(e1);
      lsum[rr] += bf2f(u0) + bf2f(u1);
      pm[(quad * 4 + rr) * 32 + c]      = u0;
      pm[(quad * 4 + rr) * 32 + 16 + c] = u1;
    }
    __builtin_amdgcn_s_waitcnt(0xc07f);   // lgkmcnt(0)
    __builtin_amdgcn_wave_barrier();
    bf16x8 pa = *reinterpret_cast<const bf16x8*>(pm + c * 32 + quad * 8);
    for (int dt = 0; dt < 5; dt++){
      bf16x8 bv = *reinterpret_cast<const bf16x8*>(Vb + (size_t)(dt * 16 + c) * TSEQ + kt + quad * 8);
      accd[dt] = __builtin_amdgcn_mfma_f32_16x16x32_bf16(pa, bv, accd[dt], 0, 0, 0);
    }
  }

  if (wave == 1){
    for (int dt = 0; dt < 5; dt++)
      for (int rr = 0; rr < 4; rr++) accS[dt][lane][rr] = accd[dt][rr];
    for (int rr = 0; rr < 4; rr++) lsumS[lane][rr] = lsum[rr];
  }
  __syncthreads();
  if (wave == 0){
    for (int dt = 0; dt < 5; dt++)
      for (int rr = 0; rr < 4; rr++) accd[dt][rr] += accS[dt][lane][rr];
    for (int rr = 0; rr < 4; rr++) lsum[rr] += lsumS[lane][rr];

    float inv[4];
    for (int rr = 0; rr < 4; rr++){
      float rs = lsum[rr];
      rs += __shfl_xor(rs, 1);
      rs += __shfl_xor(rs, 2);
      rs += __shfl_xor(rs, 4);
      rs += __shfl_xor(rs, 8);
      inv[rr] = (rs > 0.f) ? 1.0f / rs : 0.f;
    }
    for (int dt = 0; dt < 5; dt++)
      for (int rr = 0; rr < 4; rr++){
        int t = t0 + quad * 4 + rr;
        Oh[(size_t)t * HIDDEN + h * HD + dt * 16 + c] = f2bf(accd[dt][rr] * inv[rr]);
      }
  }
}

extern "C" void kernel_launch(void* const* d_in, const int* in_sizes, int n_in,
                              void* d_out, int out_size, void* d_ws, size_t ws_size,
                              hipStream_t stream)
{
  const void* X    = d_in[0];
  const void* rope = d_in[1];
  const int*  seg  = (const int*)d_in[2];
  const void* Wq   = d_in[3];
  const void* bq   = d_in[4];
  const void* Wp   = d_in[5];
  const void* bp   = d_in[6];

  char* ws = (char*)d_ws;
  size_t off = 0;
  auto alloc = [&](size_t bytes){ void* p = ws + off; off += (bytes + 255) & ~(size_t)255; return p; };
  int*    flag = (int*)alloc(4);
  int*    segS = (int*)alloc(TSEQ * 4);
  int*    segE = (int*)alloc(TSEQ * 4);
  ushort* Xb   = (ushort*)alloc((size_t)TSEQ * HIDDEN * 2);          // 5.24 MB (aliased by Oh later)
  ushort* Qh   = (ushort*)alloc((size_t)NH * TSEQ * HDP * 2);        // 6.29 MB
  ushort* Kh   = (ushort*)alloc((size_t)NH * TSEQ * HDP * 2);        // 6.29 MB
  ushort* Vt   = (ushort*)alloc((size_t)NH * HD * TSEQ * 2);         // 5.24 MB
  ushort* WT1  = (ushort*)alloc((size_t)3 * HIDDEN * HIDDEN * 2);    // 9.83 MB
  ushort* WT2  = (ushort*)alloc((size_t)HIDDEN * HIDDEN * 2);        // 3.28 MB
  ushort* qkv  = (ushort*)alloc((size_t)TSEQ * 3 * HIDDEN * 2);      // 15.73 MB
  ushort* Oh   = Xb;   // Xb dead after gemm<0>; attn writes Oh afterwards

  misc_k<<<9, 256, 0, stream>>>((const ushort*)X, seg, flag, segS, segE);
  prep_k<<<8960, 256, 0, stream>>>(flag, X, Wq, Wp, Xb, WT1, WT2);
  gemm_k<0><<<dim3(30, 16), 256, 0, stream>>>(Xb, WT1, bq, HIDDEN, 3 * HIDDEN, flag, qkv);
  reshape_k<<<2560, 256, 0, stream>>>(flag, qkv, rope, Qh, Kh, Vt);
  attn_k<<<2048, 128, 0, stream>>>(Qh, Kh, Vt, seg, segS, segE, Oh);
  gemm_k<1><<<dim3(10, 16), 256, 0, stream>>>(Oh, WT2, bp, HIDDEN, HIDDEN, flag, d_out);
}